// Round 2
// baseline (1101.315 us; speedup 1.0000x reference)
//
#include <hip/hip_runtime.h>
#include <cstdint>

#define F_IN  128
#define F_HID 16
#define F_OUT 138

// ---------------------------------------------------------------------------
// Detect edge_index dtype: int64 (LE, values < 2^31) -> every odd int32 word
// is zero. flag = 1 -> int64 (stride 2 int32 words), 0 -> int32.
__global__ void k_detect(const int* __restrict__ idx, int* __restrict__ flag) {
    __shared__ int nz;
    if (threadIdx.x == 0) nz = 0;
    __syncthreads();
    for (int i = threadIdx.x; i < 1024; i += blockDim.x)
        if (idx[2 * i + 1] != 0) nz = 1;
    __syncthreads();
    if (threadIdx.x == 0) *flag = (nz == 0) ? 1 : 0;
}

__global__ void k_zero(unsigned* __restrict__ p, int count) {
    int i = blockIdx.x * blockDim.x + threadIdx.x;
    if (i < count) p[i] = 0u;
}

// Degree count into 16 sub-histograms per node: deg16[v][e&15].
// Spreads same-address atomic contention 16x.
__global__ void k_count(const int* __restrict__ idx, const int* __restrict__ flag,
                        unsigned* __restrict__ deg16, int E) {
    const int mult = 1 + *flag;
    int e = blockIdx.x * blockDim.x + threadIdx.x;
    if (e < E) {
        int d = idx[((size_t)E + (size_t)e) * mult];
        atomicAdd(&deg16[(size_t)d * 16 + (e & 15)], 1u);
    }
}

// Per-block (256 nodes) sum of node totals -> blockSums
__global__ void k_reduce(const unsigned* __restrict__ deg16,
                         unsigned* __restrict__ blockSums, int n) {
    __shared__ unsigned sh[256];
    int v = blockIdx.x * 256 + threadIdx.x;
    unsigned tot = 0;
    if (v < n) {
#pragma unroll
        for (int s = 0; s < 16; ++s) tot += deg16[(size_t)v * 16 + s];
    }
    sh[threadIdx.x] = tot;
    __syncthreads();
    for (int off = 128; off > 0; off >>= 1) {
        if (threadIdx.x < off) sh[threadIdx.x] += sh[threadIdx.x + off];
        __syncthreads();
    }
    if (threadIdx.x == 0) blockSums[blockIdx.x] = sh[0];
}

// Sequential exclusive scan of ~391 block sums (single thread, ~us)
__global__ void k_scansums(unsigned* __restrict__ blockSums, int nb) {
    if (threadIdx.x == 0 && blockIdx.x == 0) {
        unsigned run = 0;
        for (int i = 0; i < nb; ++i) { unsigned t = blockSums[i]; blockSums[i] = run; run += t; }
    }
}

// Per node: CSR row ptr, per-sub-slot cursor bases (written back into deg16),
// dinv = rsqrt(1 + deg). Within-block Hillis-Steele scan of totals.
__global__ void k_applyscan(unsigned* __restrict__ deg16,
                            const unsigned* __restrict__ blockSums,
                            unsigned* __restrict__ ptr, float* __restrict__ dinv,
                            int n) {
    __shared__ unsigned sh[256];
    int tid = threadIdx.x;
    int v = blockIdx.x * 256 + tid;
    unsigned cnt[16];
    unsigned tot = 0;
    if (v < n) {
#pragma unroll
        for (int s = 0; s < 16; ++s) { cnt[s] = deg16[(size_t)v * 16 + s]; tot += cnt[s]; }
    }
    sh[tid] = tot;
    __syncthreads();
    for (int off = 1; off < 256; off <<= 1) {
        unsigned t = (tid >= off) ? sh[tid - off] : 0u;
        __syncthreads();
        sh[tid] += t;
        __syncthreads();
    }
    unsigned excl = sh[tid] - tot;   // exclusive prefix within block
    if (v < n) {
        unsigned base = blockSums[blockIdx.x] + excl;
        ptr[v] = base;
        unsigned run = base;
#pragma unroll
        for (int s = 0; s < 16; ++s) { deg16[(size_t)v * 16 + s] = run; run += cnt[s]; }
        dinv[v] = rsqrtf((float)(tot + 1u));   // +1 self-loop
        if (v == n - 1) ptr[n] = run;          // == E
    }
}

// Fill CSR col[] using the 16 sub-slot cursors (matching s = e&15 from count)
__global__ void k_fill(const int* __restrict__ idx, const int* __restrict__ flag,
                       unsigned* __restrict__ cursor, int* __restrict__ col, int E) {
    const int mult = 1 + *flag;
    int e = blockIdx.x * blockDim.x + threadIdx.x;
    if (e < E) {
        int s = idx[(size_t)e * mult];
        int d = idx[((size_t)E + (size_t)e) * mult];
        unsigned pos = atomicAdd(&cursor[(size_t)d * 16 + (e & 15)], 1u);
        col[pos] = s;
    }
}

// g1[v][j] = dinv[v] * (x[v] . W1[:,j]).  16 nodes x 16 feats per block.
__global__ void k_gemm1(const float* __restrict__ x, const float* __restrict__ W1,
                        const float* __restrict__ dinv,
                        float* __restrict__ g1, int n) {
    __shared__ float w1s[F_IN * F_HID];     // 8 KB
    __shared__ float xs[16][F_IN + 4];
    int tid = threadIdx.x;
    for (int i = tid; i < F_IN * F_HID; i += 256) w1s[i] = W1[i];
    int nb = blockIdx.x * 16;
    for (int q = tid; q < 512; q += 256) {
        int r = q >> 5, k4 = q & 31;
        int g = nb + r;
        float4 v = make_float4(0.f, 0.f, 0.f, 0.f);
        if (g < n) v = ((const float4*)x)[(size_t)g * 32 + k4];
        xs[r][k4 * 4 + 0] = v.x; xs[r][k4 * 4 + 1] = v.y;
        xs[r][k4 * 4 + 2] = v.z; xs[r][k4 * 4 + 3] = v.w;
    }
    __syncthreads();
    int r = tid >> 4, j = tid & 15;
    int g = nb + r;
    if (g < n) {
        float acc = 0.f;
#pragma unroll
        for (int k = 0; k < F_IN; ++k) acc += xs[r][k] * w1s[k * F_HID + j];
        g1[(size_t)g * F_HID + j] = acc * dinv[g];
    }
}

// Gather-side aggregation: node v, lanes j=0..15 accumulate feature j over
// CSR neighbors. Self-loop = init. Fused epilogue:
//   RELU=1: gout = relu(dinv*acc + b1[j]) * dinv   (layer-1 -> g2)
//   RELU=0: gout = dinv*acc                        (layer-2 pre-GEMM)
template <int RELU>
__global__ void k_agg(const unsigned* __restrict__ ptr, const int* __restrict__ col,
                      const float* __restrict__ gin, float* __restrict__ gout,
                      const float* __restrict__ dinv, const float* __restrict__ b1,
                      int n) {
    int tid = threadIdx.x;
    int v = blockIdx.x * 16 + (tid >> 4);
    int j = tid & 15;
    if (v >= n) return;
    float acc = gin[(size_t)v * F_HID + j];   // self-loop
    unsigned i = ptr[v], end = ptr[v + 1];
    for (; i + 4 <= end; i += 4) {
        int u0 = col[i], u1 = col[i + 1], u2 = col[i + 2], u3 = col[i + 3];
        acc += gin[(size_t)u0 * F_HID + j];
        acc += gin[(size_t)u1 * F_HID + j];
        acc += gin[(size_t)u2 * F_HID + j];
        acc += gin[(size_t)u3 * F_HID + j];
    }
    for (; i < end; ++i) acc += gin[(size_t)col[i] * F_HID + j];
    float di = dinv[v];
    if (RELU) {
        float h = fmaxf(di * acc + b1[j], 0.f);
        gout[(size_t)v * F_HID + j] = h * di;
    } else {
        gout[(size_t)v * F_HID + j] = di * acc;
    }
}

// out[v][c] = B[v] . W2[:,c] + b2[c]   (dinv already folded into B by agg2)
__global__ void k_out(const float* __restrict__ B,
                      const float* __restrict__ W2, const float* __restrict__ b2,
                      float* __restrict__ out, int n) {
    __shared__ float w2s[F_HID * F_OUT];
    __shared__ float b2s[F_OUT];
    int tid = threadIdx.x;
    for (int i = tid; i < F_HID * F_OUT; i += 256) w2s[i] = W2[i];
    if (tid < F_OUT) b2s[tid] = b2[tid];
    __syncthreads();
    int total = n * F_OUT;
    int stride = gridDim.x * blockDim.x;
    for (int i = blockIdx.x * blockDim.x + tid; i < total; i += stride) {
        int node = i / F_OUT, c = i - node * F_OUT;
        float acc = 0.f;
#pragma unroll
        for (int j = 0; j < F_HID; ++j) acc += B[(size_t)node * F_HID + j] * w2s[j * F_OUT + c];
        out[i] = acc + b2s[c];
    }
}

extern "C" void kernel_launch(void* const* d_in, const int* in_sizes, int n_in,
                              void* d_out, int out_size, void* d_ws, size_t ws_size,
                              hipStream_t stream) {
    const float* x   = (const float*)d_in[0];
    const int*   idx = (const int*)d_in[1];
    const float* W1  = (const float*)d_in[2];
    const float* b1  = (const float*)d_in[3];
    const float* W2  = (const float*)d_in[4];
    const float* b2  = (const float*)d_in[5];
    float* out = (float*)d_out;

    const int n = in_sizes[0] / F_IN;       // 100000
    const int E = in_sizes[1] / 2;          // 6400000

    // workspace layout (256B-aligned regions)
    char* ws = (char*)d_ws;
    size_t off = 0;
    auto carve = [&](size_t bytes) { char* p = ws + off; off += (bytes + 255) / 256 * 256; return p; };
    int*      flag      = (int*)carve(4);
    float*    dinv      = (float*)carve((size_t)n * 4);
    unsigned* ptr       = (unsigned*)carve(((size_t)n + 1) * 4);
    unsigned* blockSums = (unsigned*)carve(4096);
    unsigned* deg16     = (unsigned*)carve((size_t)n * 16 * 4);   // counts -> cursor bases
    float*    buf1      = (float*)carve((size_t)n * F_HID * 4);
    float*    buf2      = (float*)carve((size_t)n * F_HID * 4);
    // CSR col lives in d_out (25.6 MB <= 55.2 MB); consumed before k_out writes.
    int* col = (int*)d_out;

    const int B = 256;
    const int nbNodes = (n + B - 1) / B;            // 391
    const int nbEdges = (E + B - 1) / B;            // 25000
    const int nbAgg   = (n + 15) / 16;              // 6250

    k_detect<<<1, B, 0, stream>>>(idx, flag);
    k_zero<<<(n * 16 + B - 1) / B, B, 0, stream>>>(deg16, n * 16);
    k_count<<<nbEdges, B, 0, stream>>>(idx, flag, deg16, E);
    k_reduce<<<nbNodes, B, 0, stream>>>(deg16, blockSums, n);
    k_scansums<<<1, 64, 0, stream>>>(blockSums, nbNodes);
    k_applyscan<<<nbNodes, B, 0, stream>>>(deg16, blockSums, ptr, dinv, n);
    k_fill<<<nbEdges, B, 0, stream>>>(idx, flag, deg16, col, E);
    k_gemm1<<<nbAgg, B, 0, stream>>>(x, W1, dinv, buf1, n);
    k_agg<1><<<nbAgg, B, 0, stream>>>(ptr, col, buf1, buf2, dinv, b1, n);
    k_agg<0><<<nbAgg, B, 0, stream>>>(ptr, col, buf2, buf1, dinv, b1, n);
    k_out<<<8192, B, 0, stream>>>(buf1, W2, b2, out, n);
}